// Round 1
// baseline (1621.097 us; speedup 1.0000x reference)
//
#include <hip/hip_runtime.h>

typedef float f4 __attribute__((ext_vector_type(4)));

#define DF 128   // input feature dim
#define HID 64   // hidden dim
#define TN 64    // nodes per GEMM block

// ---------- degree / norm ----------
__global__ __launch_bounds__(256) void k_init_deg(float* __restrict__ deg, int N) {
    int i = blockIdx.x * 256 + threadIdx.x;
    if (i < N) deg[i] = 1.0f;   // self-loop weight
}

__global__ __launch_bounds__(256) void k_deg(const int* __restrict__ col,
                                             const float* __restrict__ ew,
                                             float* __restrict__ deg, int E) {
    int e = blockIdx.x * 256 + threadIdx.x;
    if (e < E) unsafeAtomicAdd(&deg[col[e]], ew[e]);
}

__global__ __launch_bounds__(256) void k_dinv(float* __restrict__ deg, int N) {
    int i = blockIdx.x * 256 + threadIdx.x;
    if (i < N) { float d = deg[i]; deg[i] = d > 0.f ? rsqrtf(d) : 0.f; }
}

__global__ __launch_bounds__(256) void k_norm(const int* __restrict__ row,
                                              const int* __restrict__ col,
                                              const float* __restrict__ ew,
                                              const float* __restrict__ dinv,
                                              float* __restrict__ norm, int E) {
    int e = blockIdx.x * 256 + threadIdx.x;
    if (e < E) norm[e] = dinv[row[e]] * ew[e] * dinv[col[e]];
}

// ---------- h = x @ W1  (N x 128 @ 128 x 64, fp32) ----------
// block = 256 threads = 16(tx: hid groups of 4) x 16(ty: node groups of 4)
// tile = 64 nodes x 64 hid, K loop over 128 in chunks of 4 with float4 LDS reads
__global__ __launch_bounds__(256) void k_gemm1(const float* __restrict__ x,
                                               const float* __restrict__ W1,
                                               float* __restrict__ h, int N) {
    __shared__ float xs[TN][DF];     // 64*128*4 = 32 KB
    __shared__ float ws[DF][HID];    // 128*64*4 = 32 KB
    int tid  = threadIdx.x;
    int node0 = blockIdx.x * TN;

    // stage x tile (64 rows x 128 floats = 2048 float4)
    for (int f = tid; f < TN * (DF / 4); f += 256) {
        int n = f >> 5, k4 = f & 31;
        f4 v = (f4)(0.f);
        if (node0 + n < N) v = ((const f4*)x)[(size_t)(node0 + n) * (DF / 4) + k4];
        *((f4*)&xs[n][k4 * 4]) = v;
    }
    // stage W1 (2048 float4)
    for (int f = tid; f < DF * HID / 4; f += 256) {
        ((f4*)ws)[f] = ((const f4*)W1)[f];
    }
    __syncthreads();

    int tx = tid & 15, ty = tid >> 4;
    f4 acc[4];
    acc[0] = acc[1] = acc[2] = acc[3] = (f4)(0.f);

    for (int k4 = 0; k4 < DF / 4; ++k4) {
        f4 xv[4];
#pragma unroll
        for (int i = 0; i < 4; ++i) xv[i] = *((const f4*)&xs[ty * 4 + i][k4 * 4]);
#pragma unroll
        for (int j = 0; j < 4; ++j) {
            f4 wv = *((const f4*)&ws[k4 * 4 + j][tx * 4]);
#pragma unroll
            for (int i = 0; i < 4; ++i) acc[i] += xv[i][j] * wv;
        }
    }

#pragma unroll
    for (int i = 0; i < 4; ++i) {
        int n = node0 + ty * 4 + i;
        if (n < N) ((f4*)h)[(size_t)n * (HID / 4) + tx] = acc[i];
    }
}

// ---------- agg init with self-loop contribution: agg[v] = dinv[v]^2 * h[v] ----------
__global__ __launch_bounds__(256) void k_self_init(const float* __restrict__ dinv,
                                                   const float* __restrict__ h,
                                                   float* __restrict__ agg, int N) {
    int t = blockIdx.x * 256 + threadIdx.x;   // N*16 threads, one float4 each
    if (t >= N * 16) return;
    int v = t >> 4;
    float di = dinv[v];
    float s = di * di;
    f4 hv = ((const f4*)h)[t];
    ((f4*)agg)[t] = s * hv;
}

// ---------- layer-1 edge scatter: agg[col] += norm_e * h[row] ----------
// 16 threads per edge, one float4 (4 features) each
__global__ __launch_bounds__(256) void k_scatter1(const int* __restrict__ row,
                                                  const int* __restrict__ col,
                                                  const float* __restrict__ norm,
                                                  const float* __restrict__ h,
                                                  float* __restrict__ agg, int E) {
    int t = blockIdx.x * 256 + threadIdx.x;
    if (t >= E * 16) return;
    int e = t >> 4, c = t & 15;
    float nrm = norm[e];
    int r = row[e], cl = col[e];
    f4 hv = ((const f4*)h)[(size_t)r * 16 + c];
    float* dst = agg + (size_t)cl * 64 + c * 4;
    unsafeAtomicAdd(dst + 0, nrm * hv.x);
    unsafeAtomicAdd(dst + 1, nrm * hv.y);
    unsafeAtomicAdd(dst + 2, nrm * hv.z);
    unsafeAtomicAdd(dst + 3, nrm * hv.w);
}

// ---------- fused relu(agg+b1) @ W2, init out with b2 + self-loop ----------
// 16 lanes per node, shuffle-reduce
__global__ __launch_bounds__(256) void k_h2(const float* __restrict__ agg,
                                            const float* __restrict__ b1,
                                            const float* __restrict__ W2,
                                            const float* __restrict__ b2,
                                            const float* __restrict__ dinv,
                                            float* __restrict__ h2,
                                            float* __restrict__ out, int N) {
    int t = blockIdx.x * 256 + threadIdx.x;
    if (t >= N * 16) return;
    int v = t >> 4, c = t & 15;
    f4 a  = ((const f4*)agg)[t];
    f4 bb = ((const f4*)b1)[c];
    f4 w  = ((const f4*)W2)[c];
    float s = fmaxf(a.x + bb.x, 0.f) * w.x
            + fmaxf(a.y + bb.y, 0.f) * w.y
            + fmaxf(a.z + bb.z, 0.f) * w.z
            + fmaxf(a.w + bb.w, 0.f) * w.w;
    s += __shfl_down(s, 8);
    s += __shfl_down(s, 4);
    s += __shfl_down(s, 2);
    s += __shfl_down(s, 1);
    if ((t & 15) == 0) {
        float di = dinv[v];
        h2[v] = s;
        out[v] = b2[0] + di * di * s;
    }
}

// ---------- layer-2 edge scatter: out[col] += norm_e * h2[row] ----------
__global__ __launch_bounds__(256) void k_scatter2(const int* __restrict__ row,
                                                  const int* __restrict__ col,
                                                  const float* __restrict__ norm,
                                                  const float* __restrict__ h2,
                                                  float* __restrict__ out, int E) {
    int e = blockIdx.x * 256 + threadIdx.x;
    if (e < E) unsafeAtomicAdd(&out[col[e]], norm[e] * h2[row[e]]);
}

extern "C" void kernel_launch(void* const* d_in, const int* in_sizes, int n_in,
                              void* d_out, int out_size, void* d_ws, size_t ws_size,
                              hipStream_t stream) {
    const float* x  = (const float*)d_in[0];
    const int*   ei = (const int*)d_in[1];
    const float* ew = (const float*)d_in[2];
    const float* W1 = (const float*)d_in[3];
    const float* b1 = (const float*)d_in[4];
    const float* W2 = (const float*)d_in[5];
    const float* b2 = (const float*)d_in[6];
    float* out = (float*)d_out;

    const int N = in_sizes[0] / DF;       // 100000
    const int E = in_sizes[2];            // 1600000
    const int* row = ei;                  // edge_index[0] = sources
    const int* col = ei + E;              // edge_index[1] = targets

    // workspace layout (floats)
    float* dinv = (float*)d_ws;           // N      (deg -> dinv in place)
    float* norm = dinv + N;               // E
    float* h    = norm + E;               // N*64
    float* agg  = h + (size_t)N * HID;    // N*64
    float* h2   = agg + (size_t)N * HID;  // N

    const int B = 256;
    int gN   = (N + B - 1) / B;
    int gE   = (E + B - 1) / B;
    int gN16 = (N * 16 + B - 1) / B;
    int gE16 = (E * 16 + B - 1) / B;
    int gG   = (N + TN - 1) / TN;

    k_init_deg<<<gN, B, 0, stream>>>(dinv, N);
    k_deg<<<gE, B, 0, stream>>>(col, ew, dinv, E);
    k_dinv<<<gN, B, 0, stream>>>(dinv, N);
    k_norm<<<gE, B, 0, stream>>>(row, col, ew, dinv, norm, E);
    k_gemm1<<<gG, B, 0, stream>>>(x, W1, h, N);
    k_self_init<<<gN16, B, 0, stream>>>(dinv, h, agg, N);
    k_scatter1<<<gE16, B, 0, stream>>>(row, col, norm, h, agg, E);
    k_h2<<<gN16, B, 0, stream>>>(agg, b1, W2, b2, dinv, h2, out, N);
    k_scatter2<<<gE, B, 0, stream>>>(row, col, norm, h2, out, E);
}

// Round 2
// 487.311 us; speedup vs baseline: 3.3266x; 3.3266x over previous
//
#include <hip/hip_runtime.h>

typedef float f4 __attribute__((ext_vector_type(4)));

#define DF 128   // input feature dim
#define HID 64   // hidden dim
#define TN 64    // nodes per GEMM block
#define SCAN_CHUNK 1024   // elements per scan block (256 threads x 4)

// ---------- init: deg=1 (self-loop), counts=0 ----------
__global__ __launch_bounds__(256) void k_init(float* __restrict__ deg,
                                              int* __restrict__ counts, int N) {
    int i = blockIdx.x * 256 + threadIdx.x;
    if (i < N) { deg[i] = 1.0f; counts[i] = 0; }
}

// ---------- fused degree + histogram ----------
__global__ __launch_bounds__(256) void k_deg_count(const int* __restrict__ col,
                                                   const float* __restrict__ ew,
                                                   float* __restrict__ deg,
                                                   int* __restrict__ counts, int E) {
    int e = blockIdx.x * 256 + threadIdx.x;
    if (e < E) {
        int c = col[e];
        unsafeAtomicAdd(&deg[c], ew[e]);
        atomicAdd(&counts[c], 1);
    }
}

__global__ __launch_bounds__(256) void k_dinv(float* __restrict__ deg, int N) {
    int i = blockIdx.x * 256 + threadIdx.x;
    if (i < N) { float d = deg[i]; deg[i] = d > 0.f ? rsqrtf(d) : 0.f; }
}

// ---------- 2-level exclusive scan of counts -> off ----------
__global__ __launch_bounds__(256) void k_scan1(const int* __restrict__ counts,
                                               int* __restrict__ off,
                                               int* __restrict__ bsum, int N) {
    __shared__ int lds[256];
    int tid = threadIdx.x;
    int base = blockIdx.x * SCAN_CHUNK + tid * 4;
    int c[4], s = 0;
#pragma unroll
    for (int j = 0; j < 4; ++j) { c[j] = (base + j < N) ? counts[base + j] : 0; s += c[j]; }
    lds[tid] = s; __syncthreads();
    for (int d = 1; d < 256; d <<= 1) {
        int t = (tid >= d) ? lds[tid - d] : 0;
        __syncthreads();
        lds[tid] += t;
        __syncthreads();
    }
    int run = lds[tid] - s;   // exclusive prefix within chunk
#pragma unroll
    for (int j = 0; j < 4; ++j) {
        if (base + j < N) off[base + j] = run;
        run += c[j];
    }
    if (tid == 255) bsum[blockIdx.x] = lds[255];
}

__global__ __launch_bounds__(256) void k_scan2(int* __restrict__ bsum, int nb,
                                               int* __restrict__ off, int N, int E) {
    __shared__ int lds[256];
    int tid = threadIdx.x;
    int v = (tid < nb) ? bsum[tid] : 0;
    lds[tid] = v; __syncthreads();
    for (int d = 1; d < 256; d <<= 1) {
        int t = (tid >= d) ? lds[tid - d] : 0;
        __syncthreads();
        lds[tid] += t;
        __syncthreads();
    }
    if (tid < nb) bsum[tid] = lds[tid] - v;  // exclusive
    if (tid == 0) off[N] = E;
}

// off[i] += bsum[chunk]; cur[i] = off[i]. Grid must be nb*4 blocks (1024/256).
__global__ __launch_bounds__(256) void k_scan3(int* __restrict__ off,
                                               const int* __restrict__ bsum,
                                               int* __restrict__ cur, int N) {
    int i = blockIdx.x * 256 + threadIdx.x;
    if (i < N) {
        int o = off[i] + bsum[blockIdx.x >> 2];
        off[i] = o;
        cur[i] = o;
    }
}

// ---------- bucket placement: compute norm, scatter (row, norm) sorted by col ----------
__global__ __launch_bounds__(256) void k_place(const int* __restrict__ row,
                                               const int* __restrict__ col,
                                               const float* __restrict__ ew,
                                               const float* __restrict__ dinv,
                                               int* __restrict__ cur,
                                               int* __restrict__ ssrc,
                                               float* __restrict__ snrm, int E) {
    int e = blockIdx.x * 256 + threadIdx.x;
    if (e < E) {
        int r = row[e], c = col[e];
        float nrm = dinv[r] * ew[e] * dinv[c];
        int p = atomicAdd(&cur[c], 1);
        ssrc[p] = r;
        snrm[p] = nrm;
    }
}

// ---------- h = x @ W1  (N x 128 @ 128 x 64, fp32) ----------
__global__ __launch_bounds__(256) void k_gemm1(const float* __restrict__ x,
                                               const float* __restrict__ W1,
                                               float* __restrict__ h, int N) {
    __shared__ float xs[TN][DF];     // 32 KB
    __shared__ float ws[DF][HID];    // 32 KB
    int tid  = threadIdx.x;
    int node0 = blockIdx.x * TN;

    for (int f = tid; f < TN * (DF / 4); f += 256) {
        int n = f >> 5, k4 = f & 31;
        f4 v = (f4)(0.f);
        if (node0 + n < N) v = ((const f4*)x)[(size_t)(node0 + n) * (DF / 4) + k4];
        *((f4*)&xs[n][k4 * 4]) = v;
    }
    for (int f = tid; f < DF * HID / 4; f += 256) {
        ((f4*)ws)[f] = ((const f4*)W1)[f];
    }
    __syncthreads();

    int tx = tid & 15, ty = tid >> 4;
    f4 acc[4];
    acc[0] = acc[1] = acc[2] = acc[3] = (f4)(0.f);

    for (int k4 = 0; k4 < DF / 4; ++k4) {
        f4 xv[4];
#pragma unroll
        for (int i = 0; i < 4; ++i) xv[i] = *((const f4*)&xs[ty * 4 + i][k4 * 4]);
#pragma unroll
        for (int j = 0; j < 4; ++j) {
            f4 wv = *((const f4*)&ws[k4 * 4 + j][tx * 4]);
#pragma unroll
            for (int i = 0; i < 4; ++i) acc[i] += xv[i][j] * wv;
        }
    }

#pragma unroll
    for (int i = 0; i < 4; ++i) {
        int n = node0 + ty * 4 + i;
        if (n < N) ((f4*)h)[(size_t)n * (HID / 4) + tx] = acc[i];
    }
}

// ---------- layer-1 aggregation as CSR gather: one wave per node ----------
__global__ __launch_bounds__(256) void k_agg(const int* __restrict__ off,
                                             const int* __restrict__ ssrc,
                                             const float* __restrict__ snrm,
                                             const float* __restrict__ dinv,
                                             const float* __restrict__ h,
                                             float* __restrict__ agg, int N) {
    int v = blockIdx.x * 4 + (threadIdx.x >> 6);
    if (v >= N) return;
    int l = threadIdx.x & 63;
    float di = dinv[v];
    float acc = di * di * h[(size_t)v * 64 + l];   // self-loop
    int i = off[v], e0 = off[v + 1];
    for (; i + 1 < e0; i += 2) {
        int s1 = ssrc[i], s2 = ssrc[i + 1];
        float w1 = snrm[i], w2 = snrm[i + 1];
        float h1 = h[(size_t)s1 * 64 + l];
        float h2v = h[(size_t)s2 * 64 + l];
        acc += w1 * h1;
        acc += w2 * h2v;
    }
    if (i < e0) acc += snrm[i] * h[(size_t)ssrc[i] * 64 + l];
    agg[(size_t)v * 64 + l] = acc;
}

// ---------- fused relu(agg+b1) @ W2 -> h2 ----------
__global__ __launch_bounds__(256) void k_h2(const float* __restrict__ agg,
                                            const float* __restrict__ b1,
                                            const float* __restrict__ W2,
                                            float* __restrict__ h2, int N) {
    int t = blockIdx.x * 256 + threadIdx.x;
    if (t >= N * 16) return;
    int v = t >> 4, c = t & 15;
    f4 a  = ((const f4*)agg)[t];
    f4 bb = ((const f4*)b1)[c];
    f4 w  = ((const f4*)W2)[c];
    float s = fmaxf(a.x + bb.x, 0.f) * w.x
            + fmaxf(a.y + bb.y, 0.f) * w.y
            + fmaxf(a.z + bb.z, 0.f) * w.z
            + fmaxf(a.w + bb.w, 0.f) * w.w;
    s += __shfl_down(s, 8);
    s += __shfl_down(s, 4);
    s += __shfl_down(s, 2);
    s += __shfl_down(s, 1);
    if ((t & 15) == 0) h2[v] = s;
}

// ---------- layer-2 aggregation as CSR gather: one thread per node ----------
__global__ __launch_bounds__(256) void k_out(const int* __restrict__ off,
                                             const int* __restrict__ ssrc,
                                             const float* __restrict__ snrm,
                                             const float* __restrict__ dinv,
                                             const float* __restrict__ h2,
                                             const float* __restrict__ b2,
                                             float* __restrict__ out, int N) {
    int v = blockIdx.x * 256 + threadIdx.x;
    if (v >= N) return;
    float di = dinv[v];
    float s = b2[0] + di * di * h2[v];   // self-loop
    int e0 = off[v + 1];
    for (int i = off[v]; i < e0; ++i)
        s += snrm[i] * h2[ssrc[i]];
    out[v] = s;
}

extern "C" void kernel_launch(void* const* d_in, const int* in_sizes, int n_in,
                              void* d_out, int out_size, void* d_ws, size_t ws_size,
                              hipStream_t stream) {
    const float* x  = (const float*)d_in[0];
    const int*   ei = (const int*)d_in[1];
    const float* ew = (const float*)d_in[2];
    const float* W1 = (const float*)d_in[3];
    const float* b1 = (const float*)d_in[4];
    const float* W2 = (const float*)d_in[5];
    const float* b2 = (const float*)d_in[6];
    float* out = (float*)d_out;

    const int N = in_sizes[0] / DF;       // 100000
    const int E = in_sizes[2];            // 1600000
    const int* row = ei;                  // sources
    const int* col = ei + E;              // targets

    // workspace layout (4-byte elems); h/agg offsets are multiples of 4 for f4
    float* dinv  = (float*)d_ws;                    // N
    float* h     = dinv + N;                        // N*64  (offset N=100000, %4==0)
    float* agg   = h + (size_t)N * HID;             // N*64
    float* h2    = agg + (size_t)N * HID;           // N
    int*   counts= (int*)(h2 + N);                  // N
    int*   off   = counts + N;                      // N+1
    int*   cur   = off + N + 1;                     // N
    int*   bsum  = cur + N;                         // nb (<=128)
    int*   ssrc  = bsum + 128;                      // E
    float* snrm  = (float*)(ssrc + E);              // E

    const int B = 256;
    int gN  = (N + B - 1) / B;
    int gE  = (E + B - 1) / B;
    int nb  = (N + SCAN_CHUNK - 1) / SCAN_CHUNK;    // 98
    int gN16 = (N * 16 + B - 1) / B;
    int gG  = (N + TN - 1) / TN;
    int gAgg = (N + 3) / 4;

    k_init<<<gN, B, 0, stream>>>(dinv, counts, N);
    k_deg_count<<<gE, B, 0, stream>>>(col, ew, dinv, counts, E);
    k_dinv<<<gN, B, 0, stream>>>(dinv, N);
    k_scan1<<<nb, B, 0, stream>>>(counts, off, bsum, N);
    k_scan2<<<1, B, 0, stream>>>(bsum, nb, off, N, E);
    k_scan3<<<nb * 4, B, 0, stream>>>(off, bsum, cur, N);
    k_place<<<gE, B, 0, stream>>>(row, col, ew, dinv, cur, ssrc, snrm, E);
    k_gemm1<<<gG, B, 0, stream>>>(x, W1, h, N);
    k_agg<<<gAgg, B, 0, stream>>>(off, ssrc, snrm, dinv, h, agg, N);
    k_h2<<<gN16, B, 0, stream>>>(agg, b1, W2, h2, N);
    k_out<<<gN, B, 0, stream>>>(off, ssrc, snrm, dinv, h2, b2, out, N);
}

// Round 3
// 409.393 us; speedup vs baseline: 3.9598x; 1.1903x over previous
//
#include <hip/hip_runtime.h>

typedef float f4 __attribute__((ext_vector_type(4)));

#define DF 128   // input feature dim
#define HID 64   // hidden dim
#define TN 64    // nodes per GEMM block
#define SCAN_CHUNK 1024   // elements per scan block (256 threads x 4)

// ---------- zero counts ----------
__global__ __launch_bounds__(256) void k_zero(int* __restrict__ counts, int N) {
    int i = blockIdx.x * 256 + threadIdx.x;
    if (i < N) counts[i] = 0;
}

// ---------- histogram with rank capture (the ONLY atomic pass) ----------
__global__ __launch_bounds__(256) void k_count(const int* __restrict__ col,
                                               int* __restrict__ counts,
                                               int* __restrict__ rank, int E) {
    int e = blockIdx.x * 256 + threadIdx.x;
    if (e < E) rank[e] = atomicAdd(&counts[col[e]], 1);
}

// ---------- 2-level exclusive scan of counts -> off ----------
__global__ __launch_bounds__(256) void k_scan1(const int* __restrict__ counts,
                                               int* __restrict__ off,
                                               int* __restrict__ bsum, int N) {
    __shared__ int lds[256];
    int tid = threadIdx.x;
    int base = blockIdx.x * SCAN_CHUNK + tid * 4;
    int c[4], s = 0;
#pragma unroll
    for (int j = 0; j < 4; ++j) { c[j] = (base + j < N) ? counts[base + j] : 0; s += c[j]; }
    lds[tid] = s; __syncthreads();
    for (int d = 1; d < 256; d <<= 1) {
        int t = (tid >= d) ? lds[tid - d] : 0;
        __syncthreads();
        lds[tid] += t;
        __syncthreads();
    }
    int run = lds[tid] - s;
#pragma unroll
    for (int j = 0; j < 4; ++j) {
        if (base + j < N) off[base + j] = run;
        run += c[j];
    }
    if (tid == 255) bsum[blockIdx.x] = lds[255];
}

__global__ __launch_bounds__(256) void k_scan2(int* __restrict__ bsum, int nb,
                                               int* __restrict__ off, int N, int E) {
    __shared__ int lds[256];
    int tid = threadIdx.x;
    int v = (tid < nb) ? bsum[tid] : 0;
    lds[tid] = v; __syncthreads();
    for (int d = 1; d < 256; d <<= 1) {
        int t = (tid >= d) ? lds[tid - d] : 0;
        __syncthreads();
        lds[tid] += t;
        __syncthreads();
    }
    if (tid < nb) bsum[tid] = lds[tid] - v;
    if (tid == 0) off[N] = E;
}

// off[i] += bsum[chunk]. Grid = nb*4 blocks.
__global__ __launch_bounds__(256) void k_scan3(int* __restrict__ off,
                                               const int* __restrict__ bsum, int N) {
    int i = blockIdx.x * 256 + threadIdx.x;
    if (i < N) off[i] += bsum[blockIdx.x >> 2];
}

// ---------- atomic-free placement: p = off[col] + rank ----------
__global__ __launch_bounds__(256) void k_place(const int* __restrict__ row,
                                               const int* __restrict__ col,
                                               const float* __restrict__ ew,
                                               const int* __restrict__ rank,
                                               const int* __restrict__ off,
                                               int* __restrict__ ssrc,
                                               float* __restrict__ sew, int E) {
    int e = blockIdx.x * 256 + threadIdx.x;
    if (e < E) {
        int p = off[col[e]] + rank[e];
        ssrc[p] = row[e];
        sew[p]  = ew[e];
    }
}

// ---------- deg from CSR (no atomics) + rsqrt ----------
__global__ __launch_bounds__(256) void k_dinv(const int* __restrict__ off,
                                              const float* __restrict__ sew,
                                              float* __restrict__ dinv, int N) {
    int v = blockIdx.x * 256 + threadIdx.x;
    if (v >= N) return;
    float d = 1.0f;   // self-loop
    int e0 = off[v + 1];
    for (int i = off[v]; i < e0; ++i) d += sew[i];
    dinv[v] = d > 0.f ? rsqrtf(d) : 0.f;
}

// ---------- h = x @ W1  (N x 128 @ 128 x 64, fp32) ----------
__global__ __launch_bounds__(256) void k_gemm1(const float* __restrict__ x,
                                               const float* __restrict__ W1,
                                               float* __restrict__ h, int N) {
    __shared__ float xs[TN][DF];     // 32 KB
    __shared__ float ws[DF][HID];    // 32 KB
    int tid  = threadIdx.x;
    int node0 = blockIdx.x * TN;

    for (int f = tid; f < TN * (DF / 4); f += 256) {
        int n = f >> 5, k4 = f & 31;
        f4 v = (f4)(0.f);
        if (node0 + n < N) v = ((const f4*)x)[(size_t)(node0 + n) * (DF / 4) + k4];
        *((f4*)&xs[n][k4 * 4]) = v;
    }
    for (int f = tid; f < DF * HID / 4; f += 256) {
        ((f4*)ws)[f] = ((const f4*)W1)[f];
    }
    __syncthreads();

    int tx = tid & 15, ty = tid >> 4;
    f4 acc[4];
    acc[0] = acc[1] = acc[2] = acc[3] = (f4)(0.f);

    for (int k4 = 0; k4 < DF / 4; ++k4) {
        f4 xv[4];
#pragma unroll
        for (int i = 0; i < 4; ++i) xv[i] = *((const f4*)&xs[ty * 4 + i][k4 * 4]);
#pragma unroll
        for (int j = 0; j < 4; ++j) {
            f4 wv = *((const f4*)&ws[k4 * 4 + j][tx * 4]);
#pragma unroll
            for (int i = 0; i < 4; ++i) acc[i] += xv[i][j] * wv;
        }
    }

#pragma unroll
    for (int i = 0; i < 4; ++i) {
        int n = node0 + ty * 4 + i;
        if (n < N) ((f4*)h)[(size_t)n * (HID / 4) + tx] = acc[i];
    }
}

// ---------- fused layer-1 aggregate + relu + @W2 : one wave per node ----------
// acc_l = dinv[v]*( dinv[v]*h[v,l] + sum_i dinv[src_i]*w_i*h[src_i,l] )
// h2[v] = sum_l relu(acc_l + b1[l]) * W2[l]
__global__ __launch_bounds__(256) void k_agg_h2(const int* __restrict__ off,
                                                const int* __restrict__ ssrc,
                                                const float* __restrict__ sew,
                                                const float* __restrict__ dinv,
                                                const float* __restrict__ h,
                                                const float* __restrict__ b1,
                                                const float* __restrict__ W2,
                                                float* __restrict__ h2, int N) {
    int v = blockIdx.x * 4 + (threadIdx.x >> 6);
    if (v >= N) return;
    int l = threadIdx.x & 63;
    float di = dinv[v];
    float acc = di * h[(size_t)v * 64 + l];   // self-loop (before outer di factor)
    int i = off[v], e0 = off[v + 1];
    for (; i + 1 < e0; i += 2) {
        int s1 = ssrc[i], s2 = ssrc[i + 1];
        float w1 = dinv[s1] * sew[i];
        float w2 = dinv[s2] * sew[i + 1];
        float h1 = h[(size_t)s1 * 64 + l];
        float hh2 = h[(size_t)s2 * 64 + l];
        acc += w1 * h1;
        acc += w2 * hh2;
    }
    if (i < e0) acc += dinv[ssrc[i]] * sew[i] * h[(size_t)ssrc[i] * 64 + l];
    acc = di * acc;

    float s = fmaxf(acc + b1[l], 0.f) * W2[l];
    s += __shfl_down(s, 32);
    s += __shfl_down(s, 16);
    s += __shfl_down(s, 8);
    s += __shfl_down(s, 4);
    s += __shfl_down(s, 2);
    s += __shfl_down(s, 1);
    if (l == 0) h2[v] = s;
}

// ---------- layer-2 aggregation: one thread per node ----------
__global__ __launch_bounds__(256) void k_out(const int* __restrict__ off,
                                             const int* __restrict__ ssrc,
                                             const float* __restrict__ sew,
                                             const float* __restrict__ dinv,
                                             const float* __restrict__ h2,
                                             const float* __restrict__ b2,
                                             float* __restrict__ out, int N) {
    int v = blockIdx.x * 256 + threadIdx.x;
    if (v >= N) return;
    float di = dinv[v];
    float s = di * h2[v];   // self-loop (before outer di factor)
    int e0 = off[v + 1];
    for (int i = off[v]; i < e0; ++i) {
        int src = ssrc[i];
        s += dinv[src] * sew[i] * h2[src];
    }
    out[v] = b2[0] + di * s;
}

extern "C" void kernel_launch(void* const* d_in, const int* in_sizes, int n_in,
                              void* d_out, int out_size, void* d_ws, size_t ws_size,
                              hipStream_t stream) {
    const float* x  = (const float*)d_in[0];
    const int*   ei = (const int*)d_in[1];
    const float* ew = (const float*)d_in[2];
    const float* W1 = (const float*)d_in[3];
    const float* b1 = (const float*)d_in[4];
    const float* W2 = (const float*)d_in[5];
    const float* b2 = (const float*)d_in[6];
    float* out = (float*)d_out;

    const int N = in_sizes[0] / DF;       // 100000
    const int E = in_sizes[2];            // 1600000
    const int* row = ei;                  // sources
    const int* col = ei + E;              // targets

    // workspace layout (4-byte elems); h offset multiple of 4 for f4
    float* dinv  = (float*)d_ws;                    // N
    float* h     = dinv + N;                        // N*64 (offset 100000 %4==0)
    float* h2    = h + (size_t)N * HID;             // N
    int*   counts= (int*)(h2 + N);                  // N
    int*   off   = counts + N;                      // N+1
    int*   bsum  = off + N + 1;                     // 128
    int*   rank  = bsum + 128;                      // E
    int*   ssrc  = rank + E;                        // E
    float* sew   = (float*)(ssrc + E);              // E

    const int B = 256;
    int gN  = (N + B - 1) / B;
    int gE  = (E + B - 1) / B;
    int nb  = (N + SCAN_CHUNK - 1) / SCAN_CHUNK;    // 98
    int gG  = (N + TN - 1) / TN;
    int gAgg = (N + 3) / 4;

    k_zero<<<gN, B, 0, stream>>>(counts, N);
    k_count<<<gE, B, 0, stream>>>(col, counts, rank, E);
    k_scan1<<<nb, B, 0, stream>>>(counts, off, bsum, N);
    k_scan2<<<1, B, 0, stream>>>(bsum, nb, off, N, E);
    k_scan3<<<nb * 4, B, 0, stream>>>(off, bsum, N);
    k_place<<<gE, B, 0, stream>>>(row, col, ew, rank, off, ssrc, sew, E);
    k_dinv<<<gN, B, 0, stream>>>(off, sew, dinv, N);
    k_gemm1<<<gG, B, 0, stream>>>(x, W1, h, N);
    k_agg_h2<<<gAgg, B, 0, stream>>>(off, ssrc, sew, dinv, h, b1, W2, h2, N);
    k_out<<<gN, B, 0, stream>>>(off, ssrc, sew, dinv, h2, b2, out, N);
}

// Round 4
// 329.159 us; speedup vs baseline: 4.9250x; 1.2438x over previous
//
#include <hip/hip_runtime.h>

typedef float f4 __attribute__((ext_vector_type(4)));

#define DF 128   // input feature dim
#define HID 64   // hidden dim
#define TN 64    // nodes per GEMM block
#define SCAN_CHUNK 1024   // elements per scan block (256 threads x 4)

// ---------- zero counts ----------
__global__ __launch_bounds__(256) void k_zero(int* __restrict__ counts, int N) {
    int i = blockIdx.x * 256 + threadIdx.x;
    if (i < N) counts[i] = 0;
}

// ---------- histogram with rank capture (the ONLY atomic pass) ----------
__global__ __launch_bounds__(256) void k_count(const int* __restrict__ col,
                                               int* __restrict__ counts,
                                               int* __restrict__ rank, int E) {
    int e = blockIdx.x * 256 + threadIdx.x;
    if (e < E) rank[e] = atomicAdd(&counts[col[e]], 1);
}

// ---------- 2-level exclusive scan of counts -> off ----------
__global__ __launch_bounds__(256) void k_scan1(const int* __restrict__ counts,
                                               int* __restrict__ off,
                                               int* __restrict__ bsum, int N) {
    __shared__ int lds[256];
    int tid = threadIdx.x;
    int base = blockIdx.x * SCAN_CHUNK + tid * 4;
    int c[4], s = 0;
#pragma unroll
    for (int j = 0; j < 4; ++j) { c[j] = (base + j < N) ? counts[base + j] : 0; s += c[j]; }
    lds[tid] = s; __syncthreads();
    for (int d = 1; d < 256; d <<= 1) {
        int t = (tid >= d) ? lds[tid - d] : 0;
        __syncthreads();
        lds[tid] += t;
        __syncthreads();
    }
    int run = lds[tid] - s;
#pragma unroll
    for (int j = 0; j < 4; ++j) {
        if (base + j < N) off[base + j] = run;
        run += c[j];
    }
    if (tid == 255) bsum[blockIdx.x] = lds[255];
}

__global__ __launch_bounds__(256) void k_scan2(int* __restrict__ bsum, int nb,
                                               int* __restrict__ off, int N, int E) {
    __shared__ int lds[256];
    int tid = threadIdx.x;
    int v = (tid < nb) ? bsum[tid] : 0;
    lds[tid] = v; __syncthreads();
    for (int d = 1; d < 256; d <<= 1) {
        int t = (tid >= d) ? lds[tid - d] : 0;
        __syncthreads();
        lds[tid] += t;
        __syncthreads();
    }
    if (tid < nb) bsum[tid] = lds[tid] - v;
    if (tid == 0) off[N] = E;
}

// off[i] += bsum[chunk]. Grid = nb*4 blocks.
__global__ __launch_bounds__(256) void k_scan3(int* __restrict__ off,
                                               const int* __restrict__ bsum, int N) {
    int i = blockIdx.x * 256 + threadIdx.x;
    if (i < N) off[i] += bsum[blockIdx.x >> 2];
}

// ---------- atomic-free placement: p = off[col] + rank; 8B paired store ----------
__global__ __launch_bounds__(256) void k_place(const int* __restrict__ row,
                                               const int* __restrict__ col,
                                               const float* __restrict__ ew,
                                               const int* __restrict__ rank,
                                               const int* __restrict__ off,
                                               int2* __restrict__ edata, int E) {
    int e = blockIdx.x * 256 + threadIdx.x;
    if (e < E) {
        int p = off[col[e]] + rank[e];
        int2 pr;
        pr.x = row[e];
        pr.y = __float_as_int(ew[e]);
        edata[p] = pr;
    }
}

// ---------- deg from CSR (no atomics) + rsqrt ----------
__global__ __launch_bounds__(256) void k_dinv(const int* __restrict__ off,
                                              const int2* __restrict__ edata,
                                              float* __restrict__ dinv, int N) {
    int v = blockIdx.x * 256 + threadIdx.x;
    if (v >= N) return;
    float d = 1.0f;   // self-loop
    int e0 = off[v + 1];
    for (int i = off[v]; i < e0; ++i) d += __int_as_float(edata[i].y);
    dinv[v] = d > 0.f ? rsqrtf(d) : 0.f;
}

// ---------- fold dinv[src] into edge weight: w_i *= dinv[src_i] ----------
__global__ __launch_bounds__(256) void k_snorm(int2* __restrict__ edata,
                                               const float* __restrict__ dinv, int E) {
    int i = blockIdx.x * 256 + threadIdx.x;
    if (i < E) {
        int2 pr = edata[i];
        pr.y = __float_as_int(__int_as_float(pr.y) * dinv[pr.x]);
        edata[i] = pr;
    }
}

// ---------- h = x @ W1  (N x 128 @ 128 x 64, fp32) ----------
__global__ __launch_bounds__(256) void k_gemm1(const float* __restrict__ x,
                                               const float* __restrict__ W1,
                                               float* __restrict__ h, int N) {
    __shared__ float xs[TN][DF];     // 32 KB
    __shared__ float ws[DF][HID];    // 32 KB
    int tid  = threadIdx.x;
    int node0 = blockIdx.x * TN;

    for (int f = tid; f < TN * (DF / 4); f += 256) {
        int n = f >> 5, k4 = f & 31;
        f4 v = (f4)(0.f);
        if (node0 + n < N) v = ((const f4*)x)[(size_t)(node0 + n) * (DF / 4) + k4];
        *((f4*)&xs[n][k4 * 4]) = v;
    }
    for (int f = tid; f < DF * HID / 4; f += 256) {
        ((f4*)ws)[f] = ((const f4*)W1)[f];
    }
    __syncthreads();

    int tx = tid & 15, ty = tid >> 4;
    f4 acc[4];
    acc[0] = acc[1] = acc[2] = acc[3] = (f4)(0.f);

    for (int k4 = 0; k4 < DF / 4; ++k4) {
        f4 xv[4];
#pragma unroll
        for (int i = 0; i < 4; ++i) xv[i] = *((const f4*)&xs[ty * 4 + i][k4 * 4]);
#pragma unroll
        for (int j = 0; j < 4; ++j) {
            f4 wv = *((const f4*)&ws[k4 * 4 + j][tx * 4]);
#pragma unroll
            for (int i = 0; i < 4; ++i) acc[i] += xv[i][j] * wv;
        }
    }

#pragma unroll
    for (int i = 0; i < 4; ++i) {
        int n = node0 + ty * 4 + i;
        if (n < N) ((f4*)h)[(size_t)n * (HID / 4) + tx] = acc[i];
    }
}

// ---------- fused layer-1 aggregate + relu + @W2 : one wave per node ----------
// lane-parallel edge-meta fetch + shfl broadcast; single dependent load per edge
__global__ __launch_bounds__(256) void k_agg_h2(const int* __restrict__ off,
                                                const int2* __restrict__ edata,
                                                const float* __restrict__ dinv,
                                                const float* __restrict__ h,
                                                const float* __restrict__ b1,
                                                const float* __restrict__ W2,
                                                float* __restrict__ h2, int N) {
    int v = blockIdx.x * 4 + (threadIdx.x >> 6);
    if (v >= N) return;
    int l = threadIdx.x & 63;
    float di = dinv[v];
    float acc = di * h[(size_t)v * 64 + l];   // self-loop (outer di applied later)
    int i0 = off[v], e0 = off[v + 1];

    for (int base = i0; base < e0; base += 64) {
        int idx = base + l;
        int   src_l = 0;
        float w_l   = 0.f;
        if (idx < e0) {
            int2 pr = edata[idx];
            src_l = pr.x;
            w_l   = __int_as_float(pr.y);
        }
        int cnt = min(64, e0 - base);
        int j = 0;
        for (; j + 3 < cnt; j += 4) {
            int   s0 = __shfl(src_l, j),     s1 = __shfl(src_l, j + 1);
            int   s2 = __shfl(src_l, j + 2), s3 = __shfl(src_l, j + 3);
            float w0 = __shfl(w_l, j),       w1 = __shfl(w_l, j + 1);
            float w2 = __shfl(w_l, j + 2),   w3 = __shfl(w_l, j + 3);
            float h0 = h[(size_t)s0 * 64 + l];
            float h1 = h[(size_t)s1 * 64 + l];
            float hh2 = h[(size_t)s2 * 64 + l];
            float h3 = h[(size_t)s3 * 64 + l];
            acc += w0 * h0;
            acc += w1 * h1;
            acc += w2 * hh2;
            acc += w3 * h3;
        }
        for (; j < cnt; ++j) {
            int   s = __shfl(src_l, j);
            float w = __shfl(w_l, j);
            acc += w * h[(size_t)s * 64 + l];
        }
    }
    acc = di * acc;

    float s = fmaxf(acc + b1[l], 0.f) * W2[l];
    s += __shfl_down(s, 32);
    s += __shfl_down(s, 16);
    s += __shfl_down(s, 8);
    s += __shfl_down(s, 4);
    s += __shfl_down(s, 2);
    s += __shfl_down(s, 1);
    if (l == 0) h2[v] = s;
}

// ---------- layer-2 aggregation: 16 lanes per node ----------
__global__ __launch_bounds__(256) void k_out(const int* __restrict__ off,
                                             const int2* __restrict__ edata,
                                             const float* __restrict__ dinv,
                                             const float* __restrict__ h2,
                                             const float* __restrict__ b2,
                                             float* __restrict__ out, int N) {
    int t = blockIdx.x * 256 + threadIdx.x;
    int v = t >> 4;
    if (v >= N) return;
    int c = t & 15;
    int e0 = off[v + 1];
    float s = 0.f;
    for (int i = off[v] + c; i < e0; i += 16) {
        int2 pr = edata[i];
        s += __int_as_float(pr.y) * h2[pr.x];
    }
    s += __shfl_down(s, 8);
    s += __shfl_down(s, 4);
    s += __shfl_down(s, 2);
    s += __shfl_down(s, 1);
    if (c == 0) {
        float di = dinv[v];
        out[v] = b2[0] + di * (di * h2[v] + s);
    }
}

extern "C" void kernel_launch(void* const* d_in, const int* in_sizes, int n_in,
                              void* d_out, int out_size, void* d_ws, size_t ws_size,
                              hipStream_t stream) {
    const float* x  = (const float*)d_in[0];
    const int*   ei = (const int*)d_in[1];
    const float* ew = (const float*)d_in[2];
    const float* W1 = (const float*)d_in[3];
    const float* b1 = (const float*)d_in[4];
    const float* W2 = (const float*)d_in[5];
    const float* b2 = (const float*)d_in[6];
    float* out = (float*)d_out;

    const int N = in_sizes[0] / DF;       // 100000
    const int E = in_sizes[2];            // 1600000
    const int* row = ei;                  // sources
    const int* col = ei + E;              // targets

    // workspace layout (4-byte elems); edata first for 8B alignment,
    // h element-offset multiple of 4 for f4 (16B) access
    int2*  edata = (int2*)d_ws;                     // E pairs (2E ints)
    int*   rank  = (int*)(edata + E);               // E
    float* dinv  = (float*)(rank + E);              // N
    float* h     = dinv + N;                        // N*64 (elem off = 3.2M+1.6M+100000, %4==0)
    float* h2    = h + (size_t)N * HID;             // N
    int*   counts= (int*)(h2 + N);                  // N
    int*   off   = counts + N;                      // N+1
    int*   bsum  = off + N + 1;                     // 128

    const int B = 256;
    int gN  = (N + B - 1) / B;
    int gE  = (E + B - 1) / B;
    int nb  = (N + SCAN_CHUNK - 1) / SCAN_CHUNK;    // 98
    int gG  = (N + TN - 1) / TN;
    int gAgg = (N + 3) / 4;
    int gN16 = (N * 16 + B - 1) / B;

    k_zero<<<gN, B, 0, stream>>>(counts, N);
    k_count<<<gE, B, 0, stream>>>(col, counts, rank, E);
    k_scan1<<<nb, B, 0, stream>>>(counts, off, bsum, N);
    k_scan2<<<1, B, 0, stream>>>(bsum, nb, off, N, E);
    k_scan3<<<nb * 4, B, 0, stream>>>(off, bsum, N);
    k_place<<<gE, B, 0, stream>>>(row, col, ew, rank, off, edata, E);
    k_dinv<<<gN, B, 0, stream>>>(off, edata, dinv, N);
    k_snorm<<<gE, B, 0, stream>>>(edata, dinv, E);
    k_gemm1<<<gG, B, 0, stream>>>(x, W1, h, N);
    k_agg_h2<<<gAgg, B, 0, stream>>>(off, edata, dinv, h, b1, W2, h2, N);
    k_out<<<gN16, B, 0, stream>>>(off, edata, dinv, h2, b2, out, N);
}